// Round 3
// baseline (591.139 us; speedup 1.0000x reference)
//
#include <hip/hip_runtime.h>

// NCC loss, fused single pass. Layout [n][1][d][h][w], n=2, d=160, h=192, w=192, f32.
// R3: per-slice LDS restage. Block tile 64w x 16h, streams d over CD slices.
//   Stage 1: cooperative coalesced float4 loads of the (20 rows x 72 cols x 2 arrays)
//            input tile into LDS (boundary zeros baked in -> no divergence later).
//   Stage 2: per-thread H-window accumulate from LDS (aligned ds_read_b128),
//            W-window register sliding sums, D-window 5-slot register ring.
// Rationale: R2 counters showed latency-bound (VALUBusy 31%, occ 19%) with the
// 5x H-halo re-reads thrashing L1 (54KB working set vs 32KB). LDS has 2x the BW,
// fixed low latency, and the cooperative load needs only ~3 global loads/thread/slice.

namespace {
constexpr int Wd = 192, Hd = 192, Dd = 160;
constexpr int SH = 192;             // h stride (floats)
constexpr int SD = 192 * 192;       // d stride
constexpr long SN = (long)SD * Dd;  // n stride
constexpr int CD = 6;               // d outputs per chunk; T = CD+4 = 10 (div by 5)
constexpr int NCHUNK = 27;          // ceil(160/6)
constexpr int TROW = 76;            // LDS row stride in floats (72 data + 4 pad); 304B = 16B-aligned
constexpr float INV_V = 1.0f / 125.0f;
constexpr float EPSf = 1e-5f;

__device__ __forceinline__ void wslide(const float h[8], float o[4]) {
  float s0 = h[0] + h[1] + h[2] + h[3] + h[4];
  float s1 = s0 - h[0] + h[5];
  float s2 = s1 - h[1] + h[6];
  float s3 = s2 - h[2] + h[7];
  o[0] = s0; o[1] = s1; o[2] = s2; o[3] = s3;
}
} // namespace

__global__ __launch_bounds__(256, 4) void ncc_fused(const float* __restrict__ I,
                                                    const float* __restrict__ Jv,
                                                    float* __restrict__ out) {
  __shared__ float tile[2 * 20 * TROW];   // 12.16 KB: [arr][row 0..19][col 0..71(+pad)]

  const int tid = threadIdx.x;
  const int tx = tid & 15;        // w-run index (4 outputs each)
  const int ty = tid >> 4;        // h row within 16-tall tile
  const int wbase = blockIdx.x * 64;
  const int hbase = blockIdx.y * 16;
  const int n  = blockIdx.z / NCHUNK;
  const int d_lo = (blockIdx.z % NCHUNK) * CD;

  const float* Ib = I  + (long)n * SN;
  const float* Jb = Jv + (long)n * SN;

  float ring[5][5][4];  // [phase][channel:{I,J,II,JJ,IJ}][k]
  float acc = 0.0f;

  constexpr int T = CD + 4; // 10 ring-fill steps; output d = d_lo + t - 4 for t>=4
  for (int t0 = 0; t0 < T; t0 += 5) {
    #pragma unroll
    for (int p = 0; p < 5; ++p) {           // phase = t % 5 (t0 multiple of 5)
      const int t = t0 + p;
      const int s = d_lo - 2 + t;           // slice entering the ring
      const bool svalid = (s >= 0) && (s < Dd);

      // ---- Stage 1: cooperative coalesced load of slice tile into LDS ----
      // 720 float4 tasks = 2 arrays x 20 rows x 18 segs (72 floats/row, cols wbase-4..wbase+68)
      if (svalid) {
        const float* As = Ib + (long)s * SD;
        const float* Bs = Jb + (long)s * SD;
        #pragma unroll
        for (int i = 0; i < 3; ++i) {
          const int f = tid + 256 * i;
          if (f < 720) {
            const int arr = f / 360;
            const int rem = f % 360;
            const int row = rem / 18;
            const int seg = rem % 18;
            const int hh = hbase + row - 2;
            const int gw = wbase - 4 + seg * 4;
            float4 v = make_float4(0.f, 0.f, 0.f, 0.f);
            if (hh >= 0 && hh < Hd && gw >= 0 && gw + 4 <= Wd) {
              const float* src = (arr ? Bs : As) + hh * SH + gw;
              v = *(const float4*)src;
            }
            *(float4*)&tile[(arr * 20 + row) * TROW + seg * 4] = v;
          }
        }
      }
      __syncthreads();

      // ---- Stage 2: H-window accumulate from LDS ----
      float hsI[8], hsJ[8], hsII[8], hsJJ[8], hsIJ[8];
      #pragma unroll
      for (int c = 0; c < 8; ++c) {
        hsI[c] = 0.f; hsJ[c] = 0.f; hsII[c] = 0.f; hsJJ[c] = 0.f; hsIJ[c] = 0.f;
      }
      if (svalid) {
        #pragma unroll
        for (int dh = 0; dh < 5; ++dh) {
          const int r = ty + dh;            // rows ty..ty+4  <->  hh = hbase+ty-2+dh
          const float* pa = &tile[(0 * 20 + r) * TROW + tx * 4]; // 16B-aligned
          const float* pb = &tile[(1 * 20 + r) * TROW + tx * 4];
          float a[12], b[12];
          ((float4*)a)[0] = ((const float4*)pa)[0];
          ((float4*)a)[1] = ((const float4*)pa)[1];
          ((float4*)a)[2] = ((const float4*)pa)[2];
          ((float4*)b)[0] = ((const float4*)pb)[0];
          ((float4*)b)[1] = ((const float4*)pb)[1];
          ((float4*)b)[2] = ((const float4*)pb)[2];
          #pragma unroll
          for (int c = 0; c < 8; ++c) {
            const float x = a[c + 2], y = b[c + 2];  // cols w0-2..w0+6 of the 12-wide strip
            hsI[c]  += x;
            hsJ[c]  += y;
            hsII[c] = fmaf(x, x, hsII[c]);
            hsJJ[c] = fmaf(y, y, hsJJ[c]);
            hsIJ[c] = fmaf(x, y, hsIJ[c]);
          }
        }
      }
      __syncthreads();   // reads done before next slice overwrites LDS

      // ---- W-window sliding sums -> ring ----
      wslide(hsI,  ring[p][0]);
      wslide(hsJ,  ring[p][1]);
      wslide(hsII, ring[p][2]);
      wslide(hsJJ, ring[p][3]);
      wslide(hsIJ, ring[p][4]);

      // ---- D-window + cc ----
      const int d = d_lo + t - 4;
      if (t >= 4 && d < Dd) {
        #pragma unroll
        for (int k = 0; k < 4; ++k) {
          float SI = 0.f, SJ = 0.f, SII = 0.f, SJJ = 0.f, SIJ = 0.f;
          #pragma unroll
          for (int q = 0; q < 5; ++q) {
            SI  += ring[q][0][k];
            SJ  += ring[q][1][k];
            SII += ring[q][2][k];
            SJJ += ring[q][3][k];
            SIJ += ring[q][4][k];
          }
          const float cross = SIJ - SI * SJ * INV_V;
          const float vI    = SII - SI * SI * INV_V;
          const float vJ    = SJJ - SJ * SJ * INV_V;
          acc += cross * cross / (vI * vJ + EPSf);
        }
      }
    }
  }

  // block reduction -> single atomic per block
  #pragma unroll
  for (int off = 32; off > 0; off >>= 1) acc += __shfl_xor(acc, off, 64);
  __shared__ float red[4];
  if ((tid & 63) == 0) red[tid >> 6] = acc;
  __syncthreads();
  if (tid == 0) {
    const float total = red[0] + red[1] + red[2] + red[3];
    atomicAdd(out, total * (-1.0f / 11796480.0f)); // -mean over 2*160*192*192
  }
}

extern "C" void kernel_launch(void* const* d_in, const int* in_sizes, int n_in,
                              void* d_out, int out_size, void* d_ws, size_t ws_size,
                              hipStream_t stream) {
  const float* I = (const float*)d_in[0];
  const float* J = (const float*)d_in[1];
  float* out = (float*)d_out;
  hipMemsetAsync(out, 0, sizeof(float), stream);
  dim3 grid(3, 12, 2 * NCHUNK); // W tiles * H tiles * (n x 27 d-chunks of 6)
  ncc_fused<<<grid, 256, 0, stream>>>(I, J, out);
}

// Round 5
// 163.388 us; speedup vs baseline: 3.6180x; 3.6180x over previous
//
#include <hip/hip_runtime.h>

// NCC loss, fused single pass. Layout [n][1][d][h][w], n=2, d=160, h=192, w=192, f32.
// R5: R4's double-buffered global_load_lds staging, with the DMA boundary bug fixed.
//   KEY HW FACT (guide §5, m104/m108): global_load_lds LDS dest = readfirstlane(ptr)
//   + lane*16. Per-lane exec-masking on validity shifted the base whenever lane 0
//   was masked (R4's 2.4e-4 boundary corruption). Fix: all lanes always issue the
//   DMA with CLAMPED global addresses (no per-lane validity mask; only the r=2
//   tail mask lane<52, which keeps lane 0 active). Halo correctness handled in
//   compute: H-OOB rows skipped (branch), W-OOB cols zeroed post-load (2 cols at
//   the two edge thread columns only), D-OOB slices skipped wave-uniformly.
//   LDS reads: 3x aligned ds_read_b128 per row/array (full-BW bank pattern; the
//   b64 variant is an 8-way conflict). Ring stays in registers: NO occupancy
//   clamp in __launch_bounds__ (R3's (256,4) spilled it: 1.1 GB scratch traffic).

namespace {
constexpr int Wd = 192, Hd = 192, Dd = 160;
constexpr int SH = 192;              // h stride (floats)
constexpr int SD = 192 * 192;        // d stride
constexpr long SN = (long)SD * Dd;   // n stride
constexpr int CD = 6;                // d outputs per chunk; T = CD+4 = 10
constexpr int NCHUNK = 27;           // ceil(160/6)
constexpr int TROW = 72;             // LDS row stride (floats), unpadded (DMA lane map)
constexpr int TILEF = 2 * 20 * TROW; // floats per buffer (2880)
constexpr float INV_V = 1.0f / 125.0f;
constexpr float EPSf = 1e-5f;

__device__ __forceinline__ void wslide(const float h[8], float o[4]) {
  float s0 = h[0] + h[1] + h[2] + h[3] + h[4];
  float s1 = s0 - h[0] + h[5];
  float s2 = s1 - h[1] + h[6];
  float s3 = s2 - h[2] + h[7];
  o[0] = s0; o[1] = s1; o[2] = s2; o[3] = s3;
}

__device__ __forceinline__ void gl_lds16(const float* g, float* l) {
  __builtin_amdgcn_global_load_lds(
      (const __attribute__((address_space(1))) void*)g,
      (__attribute__((address_space(3))) void*)l, 16, 0, 0);
}
} // namespace

__global__ __launch_bounds__(256) void ncc_fused(const float* __restrict__ I,
                                                 const float* __restrict__ Jv,
                                                 float* __restrict__ out) {
  __shared__ float tile[2][TILEF];   // 23.04 KB double buffer
  __shared__ float red[4];

  const int tid = threadIdx.x;
  const int tx = tid & 15;        // w-run index (4 outputs each)
  const int ty = tid >> 4;        // h row within 16-tall tile
  const int wbase = blockIdx.x * 64;
  const int hbase = blockIdx.y * 16;
  const int n  = blockIdx.z / NCHUNK;
  const int d_lo = (blockIdx.z % NCHUNK) * CD;

  const float* Ib = I  + (long)n * SN;
  const float* Jb = Jv + (long)n * SN;

  // ---- staging descriptors: 720 16B-segs; wave w owns segs [w*180,(w+1)*180) ----
  // seg = arr*360 + row*18 + c16 ; LDS byte-offset = seg*16 (consecutive per lane)
  const int wave = tid >> 6, lane = tid & 63;
  const int arr = wave >> 1;                       // waves 0,1 -> I ; 2,3 -> J
  const float* gsrc = arr ? Jb : Ib;
  int goff[3]; int loff[3]; bool on[3];
  #pragma unroll
  for (int r = 0; r < 3; ++r) {
    const int seg = wave * 180 + r * 64 + lane;
    on[r] = (r < 2) || (lane < 52);                // 180 = 2*64 + 52 (lane 0 stays active)
    const int rem = seg - arr * 360;
    const int row = rem / 18, c16 = rem % 18;
    const int hh = hbase + row - 2;
    const int hc = min(max(hh, 0), Hd - 1);        // CLAMP, never mask
    const int gw = wbase - 4 + c16 * 4;
    const int gc = min(max(gw, 0), Wd - 4);
    goff[r] = hc * SH + gc;
    loff[r] = seg * 4;                             // float offset
  }

  // ---- stage slice d_lo-2 into buffer 0 ----
  {
    const int s0 = d_lo - 2;
    if (s0 >= 0 && s0 < Dd) {
      const float* base = gsrc + (long)s0 * SD;
      #pragma unroll
      for (int r = 0; r < 3; ++r) if (on[r]) gl_lds16(base + goff[r], &tile[0][loff[r]]);
    }
  }
  __syncthreads();

  // W-edge column zero flags (cols w0-2..w0+5 needed; garbage only at these 2 threads)
  const bool zl = (wbase == 0)   && (tx == 0);   // cols -2,-1  -> a[2],a[3]
  const bool zr = (wbase == 128) && (tx == 15);  // cols 192,193 -> a[8],a[9]

  float ring[5][5][4];  // [phase][channel:{I,J,II,JJ,IJ}][k]
  float acc = 0.0f;

  constexpr int T = CD + 4; // 10 steps; output d = d_lo + t - 4 for t>=4
  for (int t0 = 0; t0 < T; t0 += 5) {
    #pragma unroll
    for (int p = 0; p < 5; ++p) {             // phase = t % 5
      const int t = t0 + p;
      const int s = d_lo - 2 + t;             // slice in current buffer

      // ---- DMA slice s+1 into the other buffer (overlaps this step's compute) ----
      {
        const int sn = s + 1;
        if ((t + 1) < T && sn >= 0 && sn < Dd) {   // wave-uniform condition
          const float* base = gsrc + (long)sn * SD;
          float* dst = &tile[(t + 1) & 1][0];
          #pragma unroll
          for (int r = 0; r < 3; ++r) if (on[r]) gl_lds16(base + goff[r], dst + loff[r]);
        }
      }

      // ---- H-window accumulate from current buffer ----
      float hsI[8], hsJ[8], hsII[8], hsJJ[8], hsIJ[8];
      #pragma unroll
      for (int c = 0; c < 8; ++c) {
        hsI[c] = 0.f; hsJ[c] = 0.f; hsII[c] = 0.f; hsJJ[c] = 0.f; hsIJ[c] = 0.f;
      }
      if (s >= 0 && s < Dd) {
        const float* bufc = &tile[t & 1][0];
        #pragma unroll
        for (int dh = 0; dh < 5; ++dh) {
          const int rrow = ty + dh;            // rows ty..ty+4 <-> hh = hbase+ty-2+dh
          const int hh = hbase + rrow - 2;
          if (hh >= 0 && hh < Hd) {            // skip clamped-duplicate halo rows
            const float* pa = bufc + rrow * TROW + 4 * tx;  // 16B-aligned
            const float* pb = pa + 20 * TROW;  // J array
            float a[12], b[12];
            ((float4*)a)[0] = ((const float4*)pa)[0];
            ((float4*)a)[1] = ((const float4*)pa)[1];
            ((float4*)a)[2] = ((const float4*)pa)[2];
            ((float4*)b)[0] = ((const float4*)pb)[0];
            ((float4*)b)[1] = ((const float4*)pb)[1];
            ((float4*)b)[2] = ((const float4*)pb)[2];
            if (zl) { a[2] = 0.f; a[3] = 0.f; b[2] = 0.f; b[3] = 0.f; }
            if (zr) { a[8] = 0.f; a[9] = 0.f; b[8] = 0.f; b[9] = 0.f; }
            #pragma unroll
            for (int c = 0; c < 8; ++c) {
              const float x = a[c + 2], y = b[c + 2];  // cols w0-2..w0+5
              hsI[c]  += x;
              hsJ[c]  += y;
              hsII[c] = fmaf(x, x, hsII[c]);
              hsJJ[c] = fmaf(y, y, hsJJ[c]);
              hsIJ[c] = fmaf(x, y, hsIJ[c]);
            }
          }
        }
      }

      // ---- W-window sliding sums -> ring ----
      wslide(hsI,  ring[p][0]);
      wslide(hsJ,  ring[p][1]);
      wslide(hsII, ring[p][2]);
      wslide(hsJJ, ring[p][3]);
      wslide(hsIJ, ring[p][4]);

      // ---- D-window + cc ----
      const int d = d_lo + t - 4;
      if (t >= 4 && d < Dd) {
        #pragma unroll
        for (int k = 0; k < 4; ++k) {
          float SI = 0.f, SJ = 0.f, SII = 0.f, SJJ = 0.f, SIJ = 0.f;
          #pragma unroll
          for (int q = 0; q < 5; ++q) {
            SI  += ring[q][0][k];
            SJ  += ring[q][1][k];
            SII += ring[q][2][k];
            SJJ += ring[q][3][k];
            SIJ += ring[q][4][k];
          }
          const float cross = SIJ - SI * SJ * INV_V;
          const float vI    = SII - SI * SI * INV_V;
          const float vJ    = SJJ - SJ * SJ * INV_V;
          acc += cross * cross / (vI * vJ + EPSf);
        }
      }

      __syncthreads();  // drains DMA for s+1; reads of current buffer done
    }
  }

  // ---- block reduction -> single atomic per block ----
  #pragma unroll
  for (int off = 32; off > 0; off >>= 1) acc += __shfl_xor(acc, off, 64);
  if ((tid & 63) == 0) red[tid >> 6] = acc;
  __syncthreads();
  if (tid == 0) {
    const float total = red[0] + red[1] + red[2] + red[3];
    atomicAdd(out, total * (-1.0f / 11796480.0f)); // -mean over 2*160*192*192
  }
}

extern "C" void kernel_launch(void* const* d_in, const int* in_sizes, int n_in,
                              void* d_out, int out_size, void* d_ws, size_t ws_size,
                              hipStream_t stream) {
  const float* I = (const float*)d_in[0];
  const float* J = (const float*)d_in[1];
  float* out = (float*)d_out;
  hipMemsetAsync(out, 0, sizeof(float), stream);
  dim3 grid(3, 12, 2 * NCHUNK); // W tiles * H tiles * (n x 27 d-chunks of 6)
  ncc_fused<<<grid, 256, 0, stream>>>(I, J, out);
}